// Round 14
// baseline (628.441 us; speedup 1.0000x reference)
//
#include <hip/hip_runtime.h>
#include <hip/hip_fp16.h>
#include <hip/hip_cooperative_groups.h>

namespace cg = cooperative_groups;

#define N_NODES   50000
#define N_EDGES   800000
#define IN_FEAT   128
#define N_CLASSES 64
#define LDS_PAD   132   // 128 + 4 floats: row-to-row bank stride = 4, float4-aligned

// ---------------------------------------------------------------------------
// Cooperative CSR build — one kernel, grid.sync between phases:
//   P0: cnt = 0
//   P1: rank[i] = atomicAdd(&cnt[col[i]], 1)
//   P2: two-level exclusive scan of cnt -> rowptr (+ dinv = rsqrt(cnt+1))
//   P3: adj[rowptr[col[i]] + rank[i]] = row[i]   (atomic-free scatter)
// 1024 blocks x 256 threads (4 blocks/CU, ~1KB LDS) — co-resident for sure.
// ---------------------------------------------------------------------------
__global__ __launch_bounds__(256) void csr_build_kernel(const int* __restrict__ col,
                                                        const int* __restrict__ row,
                                                        int* __restrict__ cnt,
                                                        int* __restrict__ rank,
                                                        int* __restrict__ rowptr,
                                                        float* __restrict__ dinv,
                                                        int* __restrict__ adj,
                                                        int* __restrict__ bsum) {
    cg::grid_group grid = cg::this_grid();
    __shared__ int sbuf[256];
    const int t   = threadIdx.x;
    const int tid = blockIdx.x * blockDim.x + t;
    const int nth = gridDim.x * blockDim.x;
    const int nch = (N_NODES + 255) / 256;  // 196 scan chunks

    // P0: zero counts
    for (int i = tid; i < N_NODES; i += nth) cnt[i] = 0;
    grid.sync();

    // P1: count + rank (the only atomic pass)
    for (int i = tid; i < N_EDGES; i += nth) rank[i] = atomicAdd(&cnt[col[i]], 1);
    grid.sync();

    // P2a: per-chunk sums
    for (int cb = blockIdx.x; cb < nch; cb += gridDim.x) {
        int i = cb * 256 + t;
        sbuf[t] = (i < N_NODES) ? cnt[i] : 0;
        __syncthreads();
        for (int off = 128; off > 0; off >>= 1) {
            if (t < off) sbuf[t] += sbuf[t + off];
            __syncthreads();
        }
        if (t == 0) bsum[cb] = sbuf[0];
        __syncthreads();  // protect sbuf before next chunk iteration
    }
    grid.sync();

    // P2b: block 0 scans the 196 chunk sums (inclusive)
    if (blockIdx.x == 0) {
        sbuf[t] = (t < nch) ? bsum[t] : 0;
        __syncthreads();
        for (int off = 1; off < 256; off <<= 1) {
            int add = (t >= off) ? sbuf[t - off] : 0;
            __syncthreads();
            sbuf[t] += add;
            __syncthreads();
        }
        if (t < nch) bsum[t] = sbuf[t];
    }
    grid.sync();

    // P2c: apply — exclusive prefix per element + dinv
    for (int cb = blockIdx.x; cb < nch; cb += gridDim.x) {
        int i = cb * 256 + t;
        int v = (i < N_NODES) ? cnt[i] : 0;
        sbuf[t] = v;
        __syncthreads();
        for (int off = 1; off < 256; off <<= 1) {
            int add = (t >= off) ? sbuf[t - off] : 0;
            __syncthreads();
            sbuf[t] += add;
            __syncthreads();
        }
        int boff = (cb > 0) ? bsum[cb - 1] : 0;
        if (i < N_NODES) {
            rowptr[i] = boff + sbuf[t] - v;           // exclusive prefix
            dinv[i]   = rsqrtf((float)(v + 1));       // +1 self loop
        }
        if (i == N_NODES - 1) rowptr[N_NODES] = boff + sbuf[t];
        __syncthreads();  // protect sbuf before next chunk iteration
    }
    grid.sync();

    // P3: atomic-free scatter
    for (int i = tid; i < N_EDGES; i += nth)
        adj[rowptr[col[i]] + rank[i]] = row[i];
}

// ---------------------------------------------------------------------------
// Tiled u = dinv .* (x @ W^T), fp16 output.  64x64 tile per 256-thread block;
// x-tile and W in LDS (pad 132); 4x4 register tile per thread.
// ---------------------------------------------------------------------------
__global__ __launch_bounds__(256) void gemm_kernel(const float* __restrict__ x,
                                                   const float* __restrict__ W,
                                                   const float* __restrict__ dinv,
                                                   __half* __restrict__ u, int n) {
    __shared__ float xs[64][LDS_PAD];
    __shared__ float ws[64][LDS_PAD];
    int t = threadIdx.x;
    int rowbase = blockIdx.x * 64;

    for (int i = t; i < 64 * 32; i += 256) {
        int r  = i >> 5;
        int kk = i & 31;
        *(float4*)(&ws[r][kk * 4]) = *(const float4*)(W + (size_t)r * IN_FEAT + kk * 4);
        int gr = rowbase + r;
        float4 v = make_float4(0.f, 0.f, 0.f, 0.f);
        if (gr < n) v = *(const float4*)(x + (size_t)gr * IN_FEAT + kk * 4);
        *(float4*)(&xs[r][kk * 4]) = v;
    }
    __syncthreads();

    int rg = t >> 4;
    int cg2 = t & 15;
    float acc[4][4] = {};

    for (int kk = 0; kk < 32; ++kk) {
        float4 a[4], bb[4];
#pragma unroll
        for (int i = 0; i < 4; ++i) a[i]  = *(float4*)(&xs[rg + 16 * i][kk * 4]);
#pragma unroll
        for (int j = 0; j < 4; ++j) bb[j] = *(float4*)(&ws[cg2 + 16 * j][kk * 4]);
#pragma unroll
        for (int i = 0; i < 4; ++i)
#pragma unroll
            for (int j = 0; j < 4; ++j)
                acc[i][j] += a[i].x * bb[j].x + a[i].y * bb[j].y +
                             a[i].z * bb[j].z + a[i].w * bb[j].w;
    }

#pragma unroll
    for (int i = 0; i < 4; ++i) {
        int gr = rowbase + rg + 16 * i;
        if (gr < n) {
            float d = dinv[gr];
#pragma unroll
            for (int j = 0; j < 4; ++j)
                u[(size_t)gr * N_CLASSES + cg2 + 16 * j] = __float2half(d * acc[i][j]);
        }
    }
}

// ---------------------------------------------------------------------------
// Pure-sum hop on fp16 tables, fp32 accumulate.
// mode 0: w1[c] = fp16( dinv^2 * ((A+I)u)[c] )
// mode 1: out[c] = fp32( dinv   * ((A+I)w1)[c] + bias )
// ---------------------------------------------------------------------------
__global__ __launch_bounds__(256) void hop_sum_kernel(const int* __restrict__ rowptr,
                                                      const int* __restrict__ adj,
                                                      const float* __restrict__ dinv,
                                                      const __half* __restrict__ yin,
                                                      __half* __restrict__ yout_h,
                                                      float* __restrict__ yout_f,
                                                      const float* __restrict__ bias,
                                                      int mode, int n) {
    int sub  = threadIdx.x >> 6;
    int lane = threadIdx.x & 63;
    int node = blockIdx.x * 4 + sub;
    if (node >= n) return;

    int s  = rowptr[node];
    int e2 = rowptr[node + 1];

    float acc = __half2float(yin[(size_t)node * N_CLASSES + lane]);  // self loop
    int k = s;
    for (; k + 7 < e2; k += 8) {
        float v0 = __half2float(yin[(size_t)adj[k + 0] * N_CLASSES + lane]);
        float v1 = __half2float(yin[(size_t)adj[k + 1] * N_CLASSES + lane]);
        float v2 = __half2float(yin[(size_t)adj[k + 2] * N_CLASSES + lane]);
        float v3 = __half2float(yin[(size_t)adj[k + 3] * N_CLASSES + lane]);
        float v4 = __half2float(yin[(size_t)adj[k + 4] * N_CLASSES + lane]);
        float v5 = __half2float(yin[(size_t)adj[k + 5] * N_CLASSES + lane]);
        float v6 = __half2float(yin[(size_t)adj[k + 6] * N_CLASSES + lane]);
        float v7 = __half2float(yin[(size_t)adj[k + 7] * N_CLASSES + lane]);
        acc += ((v0 + v1) + (v2 + v3)) + ((v4 + v5) + (v6 + v7));
    }
    for (; k < e2; ++k)
        acc += __half2float(yin[(size_t)adj[k] * N_CLASSES + lane]);

    float d = dinv[node];
    if (mode == 0) {
        yout_h[(size_t)node * N_CLASSES + lane] = __float2half(d * d * acc);
    } else {
        yout_f[(size_t)node * N_CLASSES + lane] = d * acc + bias[lane];
    }
}

// ---------------------------------------------------------------------------
extern "C" void kernel_launch(void* const* d_in, const int* in_sizes, int n_in,
                              void* d_out, int out_size, void* d_ws, size_t ws_size,
                              hipStream_t stream) {
    const float* x     = (const float*)d_in[0];
    const int*   edges = (const int*)d_in[1];   // int64 ref -> int32 device, [2, E] flat
    const float* W     = (const float*)d_in[2]; // [64, 128]
    const float* b     = (const float*)d_in[3]; // [64]
    float*       out   = (float*)d_out;         // [N, 64]

    const int* row = edges;            // sources
    const int* col = edges + N_EDGES;  // targets

    // Workspace map — ALL RANGES DISJOINT (R5-R11 crashes were dinv/bsum overlap).
    //   cnt    [      0 ..  200,000)
    //   rowptr [262,144 ..  462,148)
    //   dinv   [524,288 ..  724,288)
    //   bsum   [786,432 ..  787,216)
    //   adj    [1,048,576 .. 4,248,576)
    //   rank   [4,718,592 .. 7,918,592)
    //   u      [8,388,608 .. 14,788,608)   fp16
    //   w1     [16,777,216 .. 23,177,216)  fp16
    char* ws = (char*)d_ws;
    int*     cnt    = (int*)(ws + 0);
    int*     rowptr = (int*)(ws + 256 * 1024);
    float*   dinv   = (float*)(ws + 512 * 1024);
    int*     bsum   = (int*)(ws + 768 * 1024);
    int*     adj    = (int*)(ws + 1024 * 1024);
    int*     rank   = (int*)(ws + 4608 * 1024);
    __half*  u      = (__half*)(ws + 8 * 1024 * 1024);
    __half*  w1     = (__half*)(ws + 16 * 1024 * 1024);

    // Cooperative CSR build: 1024 blocks x 256 threads (4 blocks/CU).
    {
        void* args[] = { (void*)&col, (void*)&row, (void*)&cnt, (void*)&rank,
                         (void*)&rowptr, (void*)&dinv, (void*)&adj, (void*)&bsum };
        hipLaunchCooperativeKernel((const void*)csr_build_kernel,
                                   dim3(1024), dim3(256), args, 0, stream);
    }

    // u = D^{-1/2} (x @ W^T)  (fp16 storage)
    gemm_kernel<<<(N_NODES + 63) / 64, 256, 0, stream>>>(x, W, dinv, u, N_NODES);

    // hop1: w1 = D^{-1} (A+I) u ;  hop2: out = D^{-1/2} (A+I) w1 + b
    hop_sum_kernel<<<(N_NODES + 3) / 4, 256, 0, stream>>>(rowptr, adj, dinv,
        u, w1, nullptr, nullptr, 0, N_NODES);
    hop_sum_kernel<<<(N_NODES + 3) / 4, 256, 0, stream>>>(rowptr, adj, dinv,
        w1, nullptr, out, b, 1, N_NODES);
}

// Round 15
// 156.759 us; speedup vs baseline: 4.0090x; 4.0090x over previous
//
#include <hip/hip_runtime.h>
#include <hip/hip_fp16.h>

#define N_NODES   50000
#define N_EDGES   800000
#define IN_FEAT   128
#define N_CLASSES 64
#define LDS_PAD   132   // 128 + 4 floats: row-to-row bank stride = 4, float4-aligned

// ---------------------------------------------------------------------------
// CSR build (rank trick, 5 dispatches):
//   zero -> count_rank (int4, atomic) -> block_sum -> apply_scan (local bsum
//   scan in LDS, no separate scan kernel) -> scatter (int4, atomic-free).
// adj is uint16 (node ids < 65536): halves scatter writes + hop adj reads.
// ---------------------------------------------------------------------------
__global__ void zero_cnt_kernel(int* __restrict__ cnt, int n) {
    int i = blockIdx.x * blockDim.x + threadIdx.x;
    if (i < n) cnt[i] = 0;
}

__global__ void count_rank_kernel(const int* __restrict__ col, int* __restrict__ cnt,
                                  int* __restrict__ rank, int e) {
    int i = (blockIdx.x * blockDim.x + threadIdx.x) * 4;
    if (i + 3 < e) {
        int4 c = *(const int4*)(col + i);
        int r0 = atomicAdd(&cnt[c.x], 1);
        int r1 = atomicAdd(&cnt[c.y], 1);
        int r2 = atomicAdd(&cnt[c.z], 1);
        int r3 = atomicAdd(&cnt[c.w], 1);
        *(int4*)(rank + i) = make_int4(r0, r1, r2, r3);
    } else {
        for (int k = i; k < e; ++k) rank[k] = atomicAdd(&cnt[col[k]], 1);
    }
}

__global__ __launch_bounds__(256) void block_sum_kernel(const int* __restrict__ cnt,
                                                        int* __restrict__ bsum, int n) {
    __shared__ int s[256];
    int t = threadIdx.x;
    int i = blockIdx.x * 256 + t;
    s[t] = (i < n) ? cnt[i] : 0;
    __syncthreads();
    for (int off = 128; off > 0; off >>= 1) {
        if (t < off) s[t] += s[t + off];
        __syncthreads();
    }
    if (t == 0) bsum[blockIdx.x] = s[0];
}

// Each block: scan ALL 196 chunk sums in LDS (cheap, removes a kernel), then
// per-element exclusive prefix for its own chunk + dinv.
__global__ __launch_bounds__(256) void apply_scan_kernel(const int* __restrict__ cnt,
                                                         const int* __restrict__ bsum,
                                                         int* __restrict__ rowptr,
                                                         float* __restrict__ dinv,
                                                         int n, int nch) {
    __shared__ int sb[256];   // scanned chunk sums
    __shared__ int s[256];
    int b = blockIdx.x, t = threadIdx.x;

    // local inclusive scan of the 196 chunk sums
    sb[t] = (t < nch) ? bsum[t] : 0;
    __syncthreads();
    for (int off = 1; off < 256; off <<= 1) {
        int add = (t >= off) ? sb[t - off] : 0;
        __syncthreads();
        sb[t] += add;
        __syncthreads();
    }

    int i = b * 256 + t;
    int v = (i < n) ? cnt[i] : 0;
    s[t] = v;
    __syncthreads();
    for (int off = 1; off < 256; off <<= 1) {
        int add = (t >= off) ? s[t - off] : 0;
        __syncthreads();
        s[t] += add;
        __syncthreads();
    }
    int boff = (b > 0) ? sb[b - 1] : 0;
    if (i < n) {
        rowptr[i] = boff + s[t] - v;                 // exclusive prefix
        dinv[i]   = rsqrtf((float)(v + 1));          // +1 self loop
    }
    if (i == n - 1) rowptr[n] = boff + s[t];
}

__global__ void scatter_kernel(const int* __restrict__ row, const int* __restrict__ col,
                               const int* __restrict__ rank, const int* __restrict__ rowptr,
                               unsigned short* __restrict__ adj, int e) {
    int i = (blockIdx.x * blockDim.x + threadIdx.x) * 4;
    if (i + 3 < e) {
        int4 r  = *(const int4*)(row + i);
        int4 c  = *(const int4*)(col + i);
        int4 rk = *(const int4*)(rank + i);
        adj[rowptr[c.x] + rk.x] = (unsigned short)r.x;
        adj[rowptr[c.y] + rk.y] = (unsigned short)r.y;
        adj[rowptr[c.z] + rk.z] = (unsigned short)r.z;
        adj[rowptr[c.w] + rk.w] = (unsigned short)r.w;
    } else {
        for (int k = i; k < e; ++k)
            adj[rowptr[col[k]] + rank[k]] = (unsigned short)row[k];
    }
}

// ---------------------------------------------------------------------------
// Tiled u = dinv .* (x @ W^T), fp16 output.  64x64 tile per 256-thread block;
// x-tile and W in LDS (pad 132); 4x4 register tile per thread.
// ---------------------------------------------------------------------------
__global__ __launch_bounds__(256) void gemm_kernel(const float* __restrict__ x,
                                                   const float* __restrict__ W,
                                                   const float* __restrict__ dinv,
                                                   __half* __restrict__ u, int n) {
    __shared__ float xs[64][LDS_PAD];
    __shared__ float ws[64][LDS_PAD];
    int t = threadIdx.x;
    int rowbase = blockIdx.x * 64;

    for (int i = t; i < 64 * 32; i += 256) {
        int r  = i >> 5;
        int kk = i & 31;
        *(float4*)(&ws[r][kk * 4]) = *(const float4*)(W + (size_t)r * IN_FEAT + kk * 4);
        int gr = rowbase + r;
        float4 v = make_float4(0.f, 0.f, 0.f, 0.f);
        if (gr < n) v = *(const float4*)(x + (size_t)gr * IN_FEAT + kk * 4);
        *(float4*)(&xs[r][kk * 4]) = v;
    }
    __syncthreads();

    int rg = t >> 4;
    int cg = t & 15;
    float acc[4][4] = {};

    for (int kk = 0; kk < 32; ++kk) {
        float4 a[4], bb[4];
#pragma unroll
        for (int i = 0; i < 4; ++i) a[i]  = *(float4*)(&xs[rg + 16 * i][kk * 4]);
#pragma unroll
        for (int j = 0; j < 4; ++j) bb[j] = *(float4*)(&ws[cg + 16 * j][kk * 4]);
#pragma unroll
        for (int i = 0; i < 4; ++i)
#pragma unroll
            for (int j = 0; j < 4; ++j)
                acc[i][j] += a[i].x * bb[j].x + a[i].y * bb[j].y +
                             a[i].z * bb[j].z + a[i].w * bb[j].w;
    }

#pragma unroll
    for (int i = 0; i < 4; ++i) {
        int gr = rowbase + rg + 16 * i;
        if (gr < n) {
            float d = dinv[gr];
#pragma unroll
            for (int j = 0; j < 4; ++j)
                u[(size_t)gr * N_CLASSES + cg + 16 * j] = __float2half(d * acc[i][j]);
        }
    }
}

// ---------------------------------------------------------------------------
// Pure-sum hop on fp16 tables, fp32 accumulate; adj is uint16.
// mode 0: w1[c] = fp16( dinv^2 * ((A+I)u)[c] )
// mode 1: out[c] = fp32( dinv   * ((A+I)w1)[c] + bias )
// ---------------------------------------------------------------------------
__global__ __launch_bounds__(256) void hop_sum_kernel(const int* __restrict__ rowptr,
                                                      const unsigned short* __restrict__ adj,
                                                      const float* __restrict__ dinv,
                                                      const __half* __restrict__ yin,
                                                      __half* __restrict__ yout_h,
                                                      float* __restrict__ yout_f,
                                                      const float* __restrict__ bias,
                                                      int mode, int n) {
    int sub  = threadIdx.x >> 6;
    int lane = threadIdx.x & 63;
    int node = blockIdx.x * 4 + sub;
    if (node >= n) return;

    int s  = rowptr[node];
    int e2 = rowptr[node + 1];

    float acc = __half2float(yin[(size_t)node * N_CLASSES + lane]);  // self loop
    int k = s;
    for (; k + 7 < e2; k += 8) {
        float v0 = __half2float(yin[(size_t)adj[k + 0] * N_CLASSES + lane]);
        float v1 = __half2float(yin[(size_t)adj[k + 1] * N_CLASSES + lane]);
        float v2 = __half2float(yin[(size_t)adj[k + 2] * N_CLASSES + lane]);
        float v3 = __half2float(yin[(size_t)adj[k + 3] * N_CLASSES + lane]);
        float v4 = __half2float(yin[(size_t)adj[k + 4] * N_CLASSES + lane]);
        float v5 = __half2float(yin[(size_t)adj[k + 5] * N_CLASSES + lane]);
        float v6 = __half2float(yin[(size_t)adj[k + 6] * N_CLASSES + lane]);
        float v7 = __half2float(yin[(size_t)adj[k + 7] * N_CLASSES + lane]);
        acc += ((v0 + v1) + (v2 + v3)) + ((v4 + v5) + (v6 + v7));
    }
    for (; k < e2; ++k)
        acc += __half2float(yin[(size_t)adj[k] * N_CLASSES + lane]);

    float d = dinv[node];
    if (mode == 0) {
        yout_h[(size_t)node * N_CLASSES + lane] = __float2half(d * d * acc);
    } else {
        yout_f[(size_t)node * N_CLASSES + lane] = d * acc + bias[lane];
    }
}

// ---------------------------------------------------------------------------
extern "C" void kernel_launch(void* const* d_in, const int* in_sizes, int n_in,
                              void* d_out, int out_size, void* d_ws, size_t ws_size,
                              hipStream_t stream) {
    const float* x     = (const float*)d_in[0];
    const int*   edges = (const int*)d_in[1];   // int64 ref -> int32 device, [2, E] flat
    const float* W     = (const float*)d_in[2]; // [64, 128]
    const float* b     = (const float*)d_in[3]; // [64]
    float*       out   = (float*)d_out;         // [N, 64]

    const int* row = edges;            // sources
    const int* col = edges + N_EDGES;  // targets

    // Workspace map — ALL RANGES DISJOINT (verified; R5-R11 crashes were a
    // dinv/bsum overlap).
    //   cnt    [      0 ..  200,000)
    //   rowptr [262,144 ..  462,148)
    //   dinv   [524,288 ..  724,288)
    //   bsum   [786,432 ..  787,216)
    //   adj    [1,048,576 .. 2,648,576)   uint16
    //   rank   [4,718,592 .. 7,918,592)
    //   u      [8,388,608 .. 14,788,608)  fp16
    //   w1     [16,777,216 .. 23,177,216) fp16
    char* ws = (char*)d_ws;
    int*            cnt    = (int*)(ws + 0);
    int*            rowptr = (int*)(ws + 256 * 1024);
    float*          dinv   = (float*)(ws + 512 * 1024);
    int*            bsum   = (int*)(ws + 768 * 1024);
    unsigned short* adj    = (unsigned short*)(ws + 1024 * 1024);
    int*            rank   = (int*)(ws + 4608 * 1024);
    __half*         u      = (__half*)(ws + 8 * 1024 * 1024);
    __half*         w1     = (__half*)(ws + 16 * 1024 * 1024);

    const int nblk  = (N_NODES + 255) / 256;       // 196
    const int eblk4 = (N_EDGES / 4 + 255) / 256;   // 782 (E divisible by 4)

    // CSR build + dinv
    zero_cnt_kernel<<<nblk, 256, 0, stream>>>(cnt, N_NODES);
    count_rank_kernel<<<eblk4, 256, 0, stream>>>(col, cnt, rank, N_EDGES);
    block_sum_kernel<<<nblk, 256, 0, stream>>>(cnt, bsum, N_NODES);
    apply_scan_kernel<<<nblk, 256, 0, stream>>>(cnt, bsum, rowptr, dinv, N_NODES, nblk);
    scatter_kernel<<<eblk4, 256, 0, stream>>>(row, col, rank, rowptr, adj, N_EDGES);

    // u = D^{-1/2} (x @ W^T)  (fp16 storage)
    gemm_kernel<<<(N_NODES + 63) / 64, 256, 0, stream>>>(x, W, dinv, u, N_NODES);

    // hop1: w1 = D^{-1} (A+I) u ;  hop2: out = D^{-1/2} (A+I) w1 + b
    hop_sum_kernel<<<(N_NODES + 3) / 4, 256, 0, stream>>>(rowptr, adj, dinv,
        u, w1, nullptr, nullptr, 0, N_NODES);
    hop_sum_kernel<<<(N_NODES + 3) / 4, 256, 0, stream>>>(rowptr, adj, dinv,
        w1, nullptr, out, b, 1, N_NODES);
}

// Round 16
// 152.591 us; speedup vs baseline: 4.1185x; 1.0273x over previous
//
#include <hip/hip_runtime.h>
#include <hip/hip_fp16.h>

#define N_NODES   50000
#define N_EDGES   800000
#define IN_FEAT   128
#define N_CLASSES 64
#define LDS_PAD   132   // 128 + 4 floats: row-to-row bank stride = 4, float4-aligned

// ---------------------------------------------------------------------------
// CSR build (rank trick):
//   zero -> count_rank (int4, atomic) -> block_sum -> apply_scan (local bsum
//   scan in LDS) -> fused {scatter | gemm} (independent work, one dispatch).
// adj is uint16 (node ids < 65536).
// ---------------------------------------------------------------------------
__global__ void zero_cnt_kernel(int* __restrict__ cnt, int n) {
    int i = blockIdx.x * blockDim.x + threadIdx.x;
    if (i < n) cnt[i] = 0;
}

__global__ void count_rank_kernel(const int* __restrict__ col, int* __restrict__ cnt,
                                  int* __restrict__ rank, int e) {
    int i = (blockIdx.x * blockDim.x + threadIdx.x) * 4;
    if (i + 3 < e) {
        int4 c = *(const int4*)(col + i);
        int r0 = atomicAdd(&cnt[c.x], 1);
        int r1 = atomicAdd(&cnt[c.y], 1);
        int r2 = atomicAdd(&cnt[c.z], 1);
        int r3 = atomicAdd(&cnt[c.w], 1);
        *(int4*)(rank + i) = make_int4(r0, r1, r2, r3);
    } else {
        for (int k = i; k < e; ++k) rank[k] = atomicAdd(&cnt[col[k]], 1);
    }
}

__global__ __launch_bounds__(256) void block_sum_kernel(const int* __restrict__ cnt,
                                                        int* __restrict__ bsum, int n) {
    __shared__ int s[256];
    int t = threadIdx.x;
    int i = blockIdx.x * 256 + t;
    s[t] = (i < n) ? cnt[i] : 0;
    __syncthreads();
    for (int off = 128; off > 0; off >>= 1) {
        if (t < off) s[t] += s[t + off];
        __syncthreads();
    }
    if (t == 0) bsum[blockIdx.x] = s[0];
}

// Each block: scan ALL 196 chunk sums in LDS, then per-element exclusive
// prefix for its own chunk + dinv.
__global__ __launch_bounds__(256) void apply_scan_kernel(const int* __restrict__ cnt,
                                                         const int* __restrict__ bsum,
                                                         int* __restrict__ rowptr,
                                                         float* __restrict__ dinv,
                                                         int n, int nch) {
    __shared__ int sb[256];   // scanned chunk sums
    __shared__ int s[256];
    int b = blockIdx.x, t = threadIdx.x;

    sb[t] = (t < nch) ? bsum[t] : 0;
    __syncthreads();
    for (int off = 1; off < 256; off <<= 1) {
        int add = (t >= off) ? sb[t - off] : 0;
        __syncthreads();
        sb[t] += add;
        __syncthreads();
    }

    int i = b * 256 + t;
    int v = (i < n) ? cnt[i] : 0;
    s[t] = v;
    __syncthreads();
    for (int off = 1; off < 256; off <<= 1) {
        int add = (t >= off) ? s[t - off] : 0;
        __syncthreads();
        s[t] += add;
        __syncthreads();
    }
    int boff = (b > 0) ? sb[b - 1] : 0;
    if (i < n) {
        rowptr[i] = boff + s[t] - v;                 // exclusive prefix
        dinv[i]   = rsqrtf((float)(v + 1));          // +1 self loop
    }
    if (i == n - 1) rowptr[n] = boff + s[t];
}

// ---------------------------------------------------------------------------
// Fused {scatter | gemm}: blocks [0, nscatter) do the atomic-free CSR fill
// (latency-bound random 2B writes); blocks [nscatter, ...) do the tiled
// u = dinv .* (x @ W^T) (LDS/FMA-bound).  Independent work, block-uniform
// branch -> one dispatch, and memory- and compute-bound blocks co-reside
// per CU (2 blocks/CU at 66KB LDS), overlapping their pipes.
// ---------------------------------------------------------------------------
__global__ __launch_bounds__(256) void scatter_gemm_kernel(
        const int* __restrict__ row, const int* __restrict__ col,
        const int* __restrict__ rank, const int* __restrict__ rowptr,
        unsigned short* __restrict__ adj,
        const float* __restrict__ x, const float* __restrict__ W,
        const float* __restrict__ dinv, __half* __restrict__ u,
        int e, int n, int nscatter) {
    __shared__ float xs[64][LDS_PAD];
    __shared__ float ws[64][LDS_PAD];

    if ((int)blockIdx.x < nscatter) {
        // ---- scatter phase (4 edges/thread, int4 streams) ----
        int i = (blockIdx.x * 256 + threadIdx.x) * 4;
        if (i + 3 < e) {
            int4 r  = *(const int4*)(row + i);
            int4 c  = *(const int4*)(col + i);
            int4 rk = *(const int4*)(rank + i);
            adj[rowptr[c.x] + rk.x] = (unsigned short)r.x;
            adj[rowptr[c.y] + rk.y] = (unsigned short)r.y;
            adj[rowptr[c.z] + rk.z] = (unsigned short)r.z;
            adj[rowptr[c.w] + rk.w] = (unsigned short)r.w;
        } else {
            for (int k = i; k < e; ++k)
                adj[rowptr[col[k]] + rank[k]] = (unsigned short)row[k];
        }
        return;
    }

    // ---- gemm phase ----
    int bid = (int)blockIdx.x - nscatter;
    int t = threadIdx.x;
    int rowbase = bid * 64;

    for (int i = t; i < 64 * 32; i += 256) {
        int r  = i >> 5;
        int kk = i & 31;
        *(float4*)(&ws[r][kk * 4]) = *(const float4*)(W + (size_t)r * IN_FEAT + kk * 4);
        int gr = rowbase + r;
        float4 v = make_float4(0.f, 0.f, 0.f, 0.f);
        if (gr < n) v = *(const float4*)(x + (size_t)gr * IN_FEAT + kk * 4);
        *(float4*)(&xs[r][kk * 4]) = v;
    }
    __syncthreads();

    int rg = t >> 4;
    int cg = t & 15;
    float acc[4][4] = {};

    for (int kk = 0; kk < 32; ++kk) {
        float4 a[4], bb[4];
#pragma unroll
        for (int i = 0; i < 4; ++i) a[i]  = *(float4*)(&xs[rg + 16 * i][kk * 4]);
#pragma unroll
        for (int j = 0; j < 4; ++j) bb[j] = *(float4*)(&ws[cg + 16 * j][kk * 4]);
#pragma unroll
        for (int i = 0; i < 4; ++i)
#pragma unroll
            for (int j = 0; j < 4; ++j)
                acc[i][j] += a[i].x * bb[j].x + a[i].y * bb[j].y +
                             a[i].z * bb[j].z + a[i].w * bb[j].w;
    }

#pragma unroll
    for (int i = 0; i < 4; ++i) {
        int gr = rowbase + rg + 16 * i;
        if (gr < n) {
            float d = dinv[gr];
#pragma unroll
            for (int j = 0; j < 4; ++j)
                u[(size_t)gr * N_CLASSES + cg + 16 * j] = __float2half(d * acc[i][j]);
        }
    }
}

// ---------------------------------------------------------------------------
// Pure-sum hop on fp16 tables, fp32 accumulate; adj is uint16.
// mode 0: w1[c] = fp16( dinv^2 * ((A+I)u)[c] )
// mode 1: out[c] = fp32( dinv   * ((A+I)w1)[c] + bias )
// ---------------------------------------------------------------------------
__global__ __launch_bounds__(256) void hop_sum_kernel(const int* __restrict__ rowptr,
                                                      const unsigned short* __restrict__ adj,
                                                      const float* __restrict__ dinv,
                                                      const __half* __restrict__ yin,
                                                      __half* __restrict__ yout_h,
                                                      float* __restrict__ yout_f,
                                                      const float* __restrict__ bias,
                                                      int mode, int n) {
    int sub  = threadIdx.x >> 6;
    int lane = threadIdx.x & 63;
    int node = blockIdx.x * 4 + sub;
    if (node >= n) return;

    int s  = rowptr[node];
    int e2 = rowptr[node + 1];

    float acc = __half2float(yin[(size_t)node * N_CLASSES + lane]);  // self loop
    int k = s;
    for (; k + 7 < e2; k += 8) {
        float v0 = __half2float(yin[(size_t)adj[k + 0] * N_CLASSES + lane]);
        float v1 = __half2float(yin[(size_t)adj[k + 1] * N_CLASSES + lane]);
        float v2 = __half2float(yin[(size_t)adj[k + 2] * N_CLASSES + lane]);
        float v3 = __half2float(yin[(size_t)adj[k + 3] * N_CLASSES + lane]);
        float v4 = __half2float(yin[(size_t)adj[k + 4] * N_CLASSES + lane]);
        float v5 = __half2float(yin[(size_t)adj[k + 5] * N_CLASSES + lane]);
        float v6 = __half2float(yin[(size_t)adj[k + 6] * N_CLASSES + lane]);
        float v7 = __half2float(yin[(size_t)adj[k + 7] * N_CLASSES + lane]);
        acc += ((v0 + v1) + (v2 + v3)) + ((v4 + v5) + (v6 + v7));
    }
    for (; k < e2; ++k)
        acc += __half2float(yin[(size_t)adj[k] * N_CLASSES + lane]);

    float d = dinv[node];
    if (mode == 0) {
        yout_h[(size_t)node * N_CLASSES + lane] = __float2half(d * d * acc);
    } else {
        yout_f[(size_t)node * N_CLASSES + lane] = d * acc + bias[lane];
    }
}

// ---------------------------------------------------------------------------
extern "C" void kernel_launch(void* const* d_in, const int* in_sizes, int n_in,
                              void* d_out, int out_size, void* d_ws, size_t ws_size,
                              hipStream_t stream) {
    const float* x     = (const float*)d_in[0];
    const int*   edges = (const int*)d_in[1];   // int64 ref -> int32 device, [2, E] flat
    const float* W     = (const float*)d_in[2]; // [64, 128]
    const float* b     = (const float*)d_in[3]; // [64]
    float*       out   = (float*)d_out;         // [N, 64]

    const int* row = edges;            // sources
    const int* col = edges + N_EDGES;  // targets

    // Workspace map — ALL RANGES DISJOINT (verified).
    //   cnt    [      0 ..  200,000)
    //   rowptr [262,144 ..  462,148)
    //   dinv   [524,288 ..  724,288)
    //   bsum   [786,432 ..  787,216)
    //   adj    [1,048,576 .. 2,648,576)   uint16
    //   rank   [4,718,592 .. 7,918,592)
    //   u      [8,388,608 .. 14,788,608)  fp16
    //   w1     [16,777,216 .. 23,177,216) fp16
    char* ws = (char*)d_ws;
    int*            cnt    = (int*)(ws + 0);
    int*            rowptr = (int*)(ws + 256 * 1024);
    float*          dinv   = (float*)(ws + 512 * 1024);
    int*            bsum   = (int*)(ws + 768 * 1024);
    unsigned short* adj    = (unsigned short*)(ws + 1024 * 1024);
    int*            rank   = (int*)(ws + 4608 * 1024);
    __half*         u      = (__half*)(ws + 8 * 1024 * 1024);
    __half*         w1     = (__half*)(ws + 16 * 1024 * 1024);

    const int nblk  = (N_NODES + 255) / 256;       // 196
    const int eblk4 = (N_EDGES / 4 + 255) / 256;   // 782 (E divisible by 4)
    const int gblk  = (N_NODES + 63) / 64;         // 782

    // CSR build + dinv
    zero_cnt_kernel<<<nblk, 256, 0, stream>>>(cnt, N_NODES);
    count_rank_kernel<<<eblk4, 256, 0, stream>>>(col, cnt, rank, N_EDGES);
    block_sum_kernel<<<nblk, 256, 0, stream>>>(cnt, bsum, N_NODES);
    apply_scan_kernel<<<nblk, 256, 0, stream>>>(cnt, bsum, rowptr, dinv, N_NODES, nblk);

    // Fused: scatter (blocks [0,eblk4)) + gemm (blocks [eblk4, eblk4+gblk))
    scatter_gemm_kernel<<<eblk4 + gblk, 256, 0, stream>>>(
        row, col, rank, rowptr, adj, x, W, dinv, u, N_EDGES, N_NODES, eblk4);

    // hop1: w1 = D^{-1} (A+I) u ;  hop2: out = D^{-1/2} (A+I) w1 + b
    hop_sum_kernel<<<(N_NODES + 3) / 4, 256, 0, stream>>>(rowptr, adj, dinv,
        u, w1, nullptr, nullptr, 0, N_NODES);
    hop_sum_kernel<<<(N_NODES + 3) / 4, 256, 0, stream>>>(rowptr, adj, dinv,
        w1, nullptr, out, b, 1, N_NODES);
}

// Round 17
// 134.255 us; speedup vs baseline: 4.6809x; 1.1366x over previous
//
#include <hip/hip_runtime.h>
#include <hip/hip_fp16.h>

#define N_NODES   50000
#define N_EDGES   800000
#define IN_FEAT   128
#define N_CLASSES 64
#define LDS_PAD   132   // 128 + 4 floats: row-to-row bank stride = 4, float4-aligned

// ---------------------------------------------------------------------------
// zero -> fused {count_rank | gemm} (parity-interleaved blocks) -> block_sum
// -> apply_scan -> scatter (standalone, full occupancy) -> hop1 -> hop2.
// adj is uint16; propagation tables fp16; per-edge dinv gathered in hop1
// (R6 proved that pattern free), so gemm needs no dinv and can run early.
// ---------------------------------------------------------------------------
__global__ void zero_cnt_kernel(int* __restrict__ cnt, int n) {
    int i = blockIdx.x * blockDim.x + threadIdx.x;
    if (i < n) cnt[i] = 0;
}

// Fused: even blocks do count+rank (4 edges/thread, int4); odd blocks do the
// tiled y = x @ W^T (no dinv -> independent of the scan chain).
__global__ __launch_bounds__(256) void count_gemm_kernel(
        const int* __restrict__ col, int* __restrict__ cnt, int* __restrict__ rank,
        const float* __restrict__ x, const float* __restrict__ W,
        __half* __restrict__ y, int e, int n) {
    __shared__ float xs[64][LDS_PAD];
    __shared__ float ws[64][LDS_PAD];
    int idx = (int)blockIdx.x >> 1;

    if ((blockIdx.x & 1) == 0) {
        // ---- count + rank ----
        int i = (idx * 256 + threadIdx.x) * 4;
        if (i + 3 < e) {
            int4 c = *(const int4*)(col + i);
            int r0 = atomicAdd(&cnt[c.x], 1);
            int r1 = atomicAdd(&cnt[c.y], 1);
            int r2 = atomicAdd(&cnt[c.z], 1);
            int r3 = atomicAdd(&cnt[c.w], 1);
            *(int4*)(rank + i) = make_int4(r0, r1, r2, r3);
        } else {
            for (int k = i; k < e; ++k) rank[k] = atomicAdd(&cnt[col[k]], 1);
        }
        return;
    }

    // ---- gemm: y = x @ W^T (fp16 out, no scaling) ----
    int t = threadIdx.x;
    int rowbase = idx * 64;

    for (int i = t; i < 64 * 32; i += 256) {
        int r  = i >> 5;
        int kk = i & 31;
        *(float4*)(&ws[r][kk * 4]) = *(const float4*)(W + (size_t)r * IN_FEAT + kk * 4);
        int gr = rowbase + r;
        float4 v = make_float4(0.f, 0.f, 0.f, 0.f);
        if (gr < n) v = *(const float4*)(x + (size_t)gr * IN_FEAT + kk * 4);
        *(float4*)(&xs[r][kk * 4]) = v;
    }
    __syncthreads();

    int rg = t >> 4;
    int cg = t & 15;
    float acc[4][4] = {};

    for (int kk = 0; kk < 32; ++kk) {
        float4 a[4], bb[4];
#pragma unroll
        for (int i = 0; i < 4; ++i) a[i]  = *(float4*)(&xs[rg + 16 * i][kk * 4]);
#pragma unroll
        for (int j = 0; j < 4; ++j) bb[j] = *(float4*)(&ws[cg + 16 * j][kk * 4]);
#pragma unroll
        for (int i = 0; i < 4; ++i)
#pragma unroll
            for (int j = 0; j < 4; ++j)
                acc[i][j] += a[i].x * bb[j].x + a[i].y * bb[j].y +
                             a[i].z * bb[j].z + a[i].w * bb[j].w;
    }

#pragma unroll
    for (int i = 0; i < 4; ++i) {
        int gr = rowbase + rg + 16 * i;
        if (gr < n) {
#pragma unroll
            for (int j = 0; j < 4; ++j)
                y[(size_t)gr * N_CLASSES + cg + 16 * j] = __float2half(acc[i][j]);
        }
    }
}

__global__ __launch_bounds__(256) void block_sum_kernel(const int* __restrict__ cnt,
                                                        int* __restrict__ bsum, int n) {
    __shared__ int s[256];
    int t = threadIdx.x;
    int i = blockIdx.x * 256 + t;
    s[t] = (i < n) ? cnt[i] : 0;
    __syncthreads();
    for (int off = 128; off > 0; off >>= 1) {
        if (t < off) s[t] += s[t + off];
        __syncthreads();
    }
    if (t == 0) bsum[blockIdx.x] = s[0];
}

// Each block: scan ALL 196 chunk sums in LDS, then per-element exclusive
// prefix for its own chunk + dinv.
__global__ __launch_bounds__(256) void apply_scan_kernel(const int* __restrict__ cnt,
                                                         const int* __restrict__ bsum,
                                                         int* __restrict__ rowptr,
                                                         float* __restrict__ dinv,
                                                         int n, int nch) {
    __shared__ int sb[256];
    __shared__ int s[256];
    int b = blockIdx.x, t = threadIdx.x;

    sb[t] = (t < nch) ? bsum[t] : 0;
    __syncthreads();
    for (int off = 1; off < 256; off <<= 1) {
        int add = (t >= off) ? sb[t - off] : 0;
        __syncthreads();
        sb[t] += add;
        __syncthreads();
    }

    int i = b * 256 + t;
    int v = (i < n) ? cnt[i] : 0;
    s[t] = v;
    __syncthreads();
    for (int off = 1; off < 256; off <<= 1) {
        int add = (t >= off) ? s[t - off] : 0;
        __syncthreads();
        s[t] += add;
        __syncthreads();
    }
    int boff = (b > 0) ? sb[b - 1] : 0;
    if (i < n) {
        rowptr[i] = boff + s[t] - v;                 // exclusive prefix
        dinv[i]   = rsqrtf((float)(v + 1));          // +1 self loop
    }
    if (i == n - 1) rowptr[n] = boff + s[t];
}

__global__ void scatter_kernel(const int* __restrict__ row, const int* __restrict__ col,
                               const int* __restrict__ rank, const int* __restrict__ rowptr,
                               unsigned short* __restrict__ adj, int e) {
    int i = (blockIdx.x * blockDim.x + threadIdx.x) * 4;
    if (i + 3 < e) {
        int4 r  = *(const int4*)(row + i);
        int4 c  = *(const int4*)(col + i);
        int4 rk = *(const int4*)(rank + i);
        adj[rowptr[c.x] + rk.x] = (unsigned short)r.x;
        adj[rowptr[c.y] + rk.y] = (unsigned short)r.y;
        adj[rowptr[c.z] + rk.z] = (unsigned short)r.z;
        adj[rowptr[c.w] + rk.w] = (unsigned short)r.w;
    } else {
        for (int k = i; k < e; ++k)
            adj[rowptr[col[k]] + rank[k]] = (unsigned short)row[k];
    }
}

// ---------------------------------------------------------------------------
// Hops on fp16 tables, fp32 accumulate; adj is uint16.
// mode 0: w1[c] = fp16( dinv[c]^2 * ( dinv[c]*y[c] + sum_r dinv[r]*y[r] ) )
//         (per-edge dinv gather: proven free in R6)
// mode 1: out[c] = fp32( dinv[c] * ( w1[c] + sum_r w1[r] ) + bias )
// ---------------------------------------------------------------------------
__global__ __launch_bounds__(256) void hop_sum_kernel(const int* __restrict__ rowptr,
                                                      const unsigned short* __restrict__ adj,
                                                      const float* __restrict__ dinv,
                                                      const __half* __restrict__ yin,
                                                      __half* __restrict__ yout_h,
                                                      float* __restrict__ yout_f,
                                                      const float* __restrict__ bias,
                                                      int mode, int n) {
    int sub  = threadIdx.x >> 6;
    int lane = threadIdx.x & 63;
    int node = blockIdx.x * 4 + sub;
    if (node >= n) return;

    int s  = rowptr[node];
    int e2 = rowptr[node + 1];
    float d = dinv[node];

    float acc;
    int k = s;
    if (mode == 0) {
        acc = d * __half2float(yin[(size_t)node * N_CLASSES + lane]);  // self
        for (; k + 7 < e2; k += 8) {
            int r0 = adj[k + 0], r1 = adj[k + 1], r2 = adj[k + 2], r3 = adj[k + 3];
            int r4 = adj[k + 4], r5 = adj[k + 5], r6 = adj[k + 6], r7 = adj[k + 7];
            float a0 = dinv[r0] * __half2float(yin[(size_t)r0 * N_CLASSES + lane]);
            float a1 = dinv[r1] * __half2float(yin[(size_t)r1 * N_CLASSES + lane]);
            float a2 = dinv[r2] * __half2float(yin[(size_t)r2 * N_CLASSES + lane]);
            float a3 = dinv[r3] * __half2float(yin[(size_t)r3 * N_CLASSES + lane]);
            float a4 = dinv[r4] * __half2float(yin[(size_t)r4 * N_CLASSES + lane]);
            float a5 = dinv[r5] * __half2float(yin[(size_t)r5 * N_CLASSES + lane]);
            float a6 = dinv[r6] * __half2float(yin[(size_t)r6 * N_CLASSES + lane]);
            float a7 = dinv[r7] * __half2float(yin[(size_t)r7 * N_CLASSES + lane]);
            acc += ((a0 + a1) + (a2 + a3)) + ((a4 + a5) + (a6 + a7));
        }
        for (; k < e2; ++k) {
            int r = adj[k];
            acc += dinv[r] * __half2float(yin[(size_t)r * N_CLASSES + lane]);
        }
        yout_h[(size_t)node * N_CLASSES + lane] = __float2half(d * d * acc);
    } else {
        acc = __half2float(yin[(size_t)node * N_CLASSES + lane]);  // self
        for (; k + 7 < e2; k += 8) {
            float v0 = __half2float(yin[(size_t)adj[k + 0] * N_CLASSES + lane]);
            float v1 = __half2float(yin[(size_t)adj[k + 1] * N_CLASSES + lane]);
            float v2 = __half2float(yin[(size_t)adj[k + 2] * N_CLASSES + lane]);
            float v3 = __half2float(yin[(size_t)adj[k + 3] * N_CLASSES + lane]);
            float v4 = __half2float(yin[(size_t)adj[k + 4] * N_CLASSES + lane]);
            float v5 = __half2float(yin[(size_t)adj[k + 5] * N_CLASSES + lane]);
            float v6 = __half2float(yin[(size_t)adj[k + 6] * N_CLASSES + lane]);
            float v7 = __half2float(yin[(size_t)adj[k + 7] * N_CLASSES + lane]);
            acc += ((v0 + v1) + (v2 + v3)) + ((v4 + v5) + (v6 + v7));
        }
        for (; k < e2; ++k)
            acc += __half2float(yin[(size_t)adj[k] * N_CLASSES + lane]);
        yout_f[(size_t)node * N_CLASSES + lane] = d * acc + bias[lane];
    }
}

// ---------------------------------------------------------------------------
extern "C" void kernel_launch(void* const* d_in, const int* in_sizes, int n_in,
                              void* d_out, int out_size, void* d_ws, size_t ws_size,
                              hipStream_t stream) {
    const float* x     = (const float*)d_in[0];
    const int*   edges = (const int*)d_in[1];   // int64 ref -> int32 device, [2, E] flat
    const float* W     = (const float*)d_in[2]; // [64, 128]
    const float* b     = (const float*)d_in[3]; // [64]
    float*       out   = (float*)d_out;         // [N, 64]

    const int* row = edges;            // sources
    const int* col = edges + N_EDGES;  // targets

    // Workspace map — ALL RANGES DISJOINT (verified).
    //   cnt    [      0 ..  200,000)
    //   rowptr [262,144 ..  462,148)
    //   dinv   [524,288 ..  724,288)
    //   bsum   [786,432 ..  787,216)
    //   adj    [1,048,576 .. 2,648,576)   uint16
    //   rank   [4,718,592 .. 7,918,592)
    //   y      [8,388,608 .. 14,788,608)  fp16
    //   w1     [16,777,216 .. 23,177,216) fp16
    char* ws = (char*)d_ws;
    int*            cnt    = (int*)(ws + 0);
    int*            rowptr = (int*)(ws + 256 * 1024);
    float*          dinv   = (float*)(ws + 512 * 1024);
    int*            bsum   = (int*)(ws + 768 * 1024);
    unsigned short* adj    = (unsigned short*)(ws + 1024 * 1024);
    int*            rank   = (int*)(ws + 4608 * 1024);
    __half*         y      = (__half*)(ws + 8 * 1024 * 1024);
    __half*         w1     = (__half*)(ws + 16 * 1024 * 1024);

    const int nblk  = (N_NODES + 255) / 256;       // 196
    const int eblk4 = (N_EDGES / 4 + 255) / 256;   // 782
    const int gblk  = (N_NODES + 63) / 64;         // 782

    // CSR build + dinv; gemm overlapped with the atomic histogram.
    zero_cnt_kernel<<<nblk, 256, 0, stream>>>(cnt, N_NODES);
    count_gemm_kernel<<<eblk4 + gblk, 256, 0, stream>>>(col, cnt, rank, x, W, y,
                                                        N_EDGES, N_NODES);
    block_sum_kernel<<<nblk, 256, 0, stream>>>(cnt, bsum, N_NODES);
    apply_scan_kernel<<<nblk, 256, 0, stream>>>(cnt, bsum, rowptr, dinv, N_NODES, nblk);
    scatter_kernel<<<eblk4, 256, 0, stream>>>(row, col, rank, rowptr, adj, N_EDGES);

    // hop1: w1 = D^{-1}(A+I)D^{-1/2} y ;  hop2: out = D^{-1/2}(A+I) w1 + b
    hop_sum_kernel<<<(N_NODES + 3) / 4, 256, 0, stream>>>(rowptr, adj, dinv,
        y, w1, nullptr, nullptr, 0, N_NODES);
    hop_sum_kernel<<<(N_NODES + 3) / 4, 256, 0, stream>>>(rowptr, adj, dinv,
        w1, nullptr, out, b, 1, N_NODES);
}